// Round 11
// baseline (167.885 us; speedup 1.0000x reference)
//
#include <hip/hip_runtime.h>

#define IN_CH 16
#define OUT_CH 16
#define EDGE_FEAT 32
#define HIDDEN 128
#define WROW 256          // IN_CH*OUT_CH
#define FN_FPB 8          // filters per block in filter-net kernel

// f16 weight row layout (512 B): 32 chunks of 16 B.
// chunk (u*4 + j), u in [0,8), j in [0,4): dword c (c in [0,4)) holds the
// f16 pair ( w[2u][4j+c] , w[2u+1][4j+c] ) — pairs run along the input
// channel so one v_dot2_f32_f16 consumes both.
// Edge-quad lane j loads chunks {u*4+j}; a quad's load u is one 64 B line.

typedef __fp16 half2_v __attribute__((ext_vector_type(2)));
typedef unsigned uvec4 __attribute__((ext_vector_type(4)));
typedef float fvec4 __attribute__((ext_vector_type(4)));

__device__ __forceinline__ unsigned pk_f16(float lo, float hi) {
  half2_v h = __builtin_amdgcn_cvt_pkrtz(lo, hi);
  return __builtin_bit_cast(unsigned, h);
}

__device__ __forceinline__ float dot2(unsigned wpair, half2_v xp, float acc) {
  half2_v w = __builtin_bit_cast(half2_v, wpair);
#if __has_builtin(__builtin_amdgcn_fdot2)
  return __builtin_amdgcn_fdot2(xp, w, acc, false);
#else
  acc = fmaf((float)xp[0], (float)w[0], acc);
  return fmaf((float)xp[1], (float)w[1], acc);
#endif
}

// ---------------- Kernel 1: filter net (f16 pair-layout output) -------------
__global__ __launch_bounds__(256) void filter_net_kernel(
    const float* __restrict__ ef, const float* __restrict__ W1,
    const float* __restrict__ b1, const float* __restrict__ W2,
    const float* __restrict__ b2, unsigned short* __restrict__ weights,
    float* __restrict__ zero_base, int nzero4) {
  const int t = threadIdx.x;
  const int f0 = blockIdx.x * FN_FPB;

  // fused zeroing of sums+deg
  for (int gid = blockIdx.x * 256 + t; gid < nzero4; gid += gridDim.x * 256)
    ((float4*)zero_base)[gid] = make_float4(0.f, 0.f, 0.f, 0.f);

  __shared__ float ef_s[FN_FPB * EDGE_FEAT];  // 256 floats
  __shared__ float h_s[FN_FPB][HIDDEN];       // 1024 floats
  ef_s[t] = ef[f0 * EDGE_FEAT + t];
  __syncthreads();

  // stage 1: 1024 h values, 4 per thread.
  #pragma unroll
  for (int r = 0; r < 4; ++r) {
    const int idx = t + r * 256;
    const int fi = idx >> 7;
    const int hi = idx & (HIDDEN - 1);
    float a = b1[hi];
    #pragma unroll
    for (int k = 0; k < EDGE_FEAT; ++k)
      a = fmaf(ef_s[fi * EDGE_FEAT + k], W1[k * HIDDEN + hi], a);
    h_s[fi][hi] = a > 0.f ? a : 0.f;
  }
  __syncthreads();

  const int fslot = t >> 5;
  const int combo = t & 31;
  const int u = combo >> 2;
  const int jo = combo & 3;
  const int colLo = 32 * u + 4 * jo;   // out col base for i = 2u
  const int colHi = colLo + 16;        // for i = 2u+1

  float4 aLo = *(const float4*)(b2 + colLo);
  float4 aHi = *(const float4*)(b2 + colHi);
  const float* __restrict__ hrow = h_s[fslot];
  #pragma unroll 4
  for (int k = 0; k < HIDDEN; ++k) {
    const float4 wLo = *(const float4*)(W2 + (size_t)k * WROW + colLo);
    const float4 wHi = *(const float4*)(W2 + (size_t)k * WROW + colHi);
    const float hv = hrow[k];
    aLo.x = fmaf(hv, wLo.x, aLo.x);
    aLo.y = fmaf(hv, wLo.y, aLo.y);
    aLo.z = fmaf(hv, wLo.z, aLo.z);
    aLo.w = fmaf(hv, wLo.w, aLo.w);
    aHi.x = fmaf(hv, wHi.x, aHi.x);
    aHi.y = fmaf(hv, wHi.y, aHi.y);
    aHi.z = fmaf(hv, wHi.z, aHi.z);
    aHi.w = fmaf(hv, wHi.w, aHi.w);
  }

  uint4 st;
  st.x = pk_f16(aLo.x, aHi.x);
  st.y = pk_f16(aLo.y, aHi.y);
  st.z = pk_f16(aLo.z, aHi.z);
  st.w = pk_f16(aLo.w, aHi.w);
  *(uint4*)(weights + (size_t)(f0 + fslot) * WROW + (u * 4 + jo) * 8) = st;
}

// ---------------- Kernel 2: r10 + read-write-pinned load batches ------------
// Lane = e16*4 + j (quad-coalesced). The "+v" asm pins force all 18 loads
// to be materialized before consumption: pin-A drains A (B stays in flight),
// dot-A overlaps B's tail, pin-B drains B. Up to ~18 line-batches
// outstanding per thread instead of the compiler's default ~2-4.

template <int CTRL, int OLD>
__device__ __forceinline__ int dpp_i(int v) {
  return __builtin_amdgcn_update_dpp(OLD, v, CTRL, 0xf, 0xf, false);
}
template <int CTRL>
__device__ __forceinline__ float dpp_f(float v) {
  return __builtin_bit_cast(
      float, __builtin_amdgcn_update_dpp(0, __builtin_bit_cast(int, v), CTRL,
                                         0xf, 0xf, false));
}
template <int Q>
__device__ __forceinline__ int quad_bcast_dpp(int v) {
  return __builtin_amdgcn_update_dpp(0, v, Q * 0x55, 0xf, 0xf, false);
}

template <int CTRL>
__device__ __forceinline__ void seg_step_dpp(int s, fvec4& acc, float& cnt) {
  const int os = dpp_i<CTRL, -1>(s);
  const float ox = dpp_f<CTRL>(acc.x);
  const float oy = dpp_f<CTRL>(acc.y);
  const float oz = dpp_f<CTRL>(acc.z);
  const float ow = dpp_f<CTRL>(acc.w);
  const float oc = dpp_f<CTRL>(cnt);
  if (os == s) {
    acc.x += ox; acc.y += oy; acc.z += oz; acc.w += ow;
    cnt += oc;
  }
}

__device__ __forceinline__ void seg_step_bperm(int src, int s, fvec4& acc,
                                               float& cnt) {
  const int os = __shfl(s, src & 63);
  const float ox = __shfl(acc.x, src & 63);
  const float oy = __shfl(acc.y, src & 63);
  const float oz = __shfl(acc.z, src & 63);
  const float ow = __shfl(acc.w, src & 63);
  const float oc = __shfl(cnt, src & 63);
  if (src < 64 && os == s) {
    acc.x += ox; acc.y += oy; acc.z += oz; acc.w += ow;
    cnt += oc;
  }
}

__device__ __forceinline__ void seg_reduce_flush(
    int s, fvec4 acc, float cnt, bool valid, int lane, int e16, int j,
    float* __restrict__ sums, float* __restrict__ deg) {
  if (!valid) {
    acc.x = 0.f; acc.y = 0.f; acc.z = 0.f; acc.w = 0.f;
    cnt = 0.f;
    s = -1;
  }
  seg_step_dpp<0x104>(s, acc, cnt);   // + edge e+1 (within 16-lane row)
  seg_step_dpp<0x108>(s, acc, cnt);   // + edges e+2,e+3
  const int rb = (lane & ~15) | (lane & 3);   // 16*r + j
  seg_step_bperm(rb + 16, s, acc, cnt);       // + next row head
  seg_step_bperm(rb + 32, s, acc, cnt);       // + rows r+2,r+3
  const int ps = __shfl(s, (lane - 4) & 63);
  const bool head = (e16 == 0) || (ps != s);
  if (valid && head && s >= 0) {
    float* p = sums + (size_t)s * OUT_CH + j * 4;
    atomicAdd(p + 0, acc.x);
    atomicAdd(p + 1, acc.y);
    atomicAdd(p + 2, acc.z);
    atomicAdd(p + 3, acc.w);
    if (j == 0) atomicAdd(deg + s, cnt);
  }
}

__device__ __forceinline__ fvec4 edge_dot(const fvec4 xo, const uvec4* wv) {
  const int p0 = (int)pk_f16(xo.x, xo.y);
  const int p1 = (int)pk_f16(xo.z, xo.w);
  half2_v xp[8];
  xp[0] = __builtin_bit_cast(half2_v, quad_bcast_dpp<0>(p0));
  xp[1] = __builtin_bit_cast(half2_v, quad_bcast_dpp<0>(p1));
  xp[2] = __builtin_bit_cast(half2_v, quad_bcast_dpp<1>(p0));
  xp[3] = __builtin_bit_cast(half2_v, quad_bcast_dpp<1>(p1));
  xp[4] = __builtin_bit_cast(half2_v, quad_bcast_dpp<2>(p0));
  xp[5] = __builtin_bit_cast(half2_v, quad_bcast_dpp<2>(p1));
  xp[6] = __builtin_bit_cast(half2_v, quad_bcast_dpp<3>(p0));
  xp[7] = __builtin_bit_cast(half2_v, quad_bcast_dpp<3>(p1));

  fvec4 acc = {0.f, 0.f, 0.f, 0.f};
  #pragma unroll
  for (int u = 0; u < 8; ++u) {
    acc.x = dot2(wv[u].x, xp[u], acc.x);
    acc.y = dot2(wv[u].y, xp[u], acc.y);
    acc.z = dot2(wv[u].z, xp[u], acc.z);
    acc.w = dot2(wv[u].w, xp[u], acc.w);
  }
  return acc;
}

__global__ __launch_bounds__(256, 4) void edge_kernel(
    const float* __restrict__ input, const int* __restrict__ idxn,
    const int* __restrict__ idxe, const int* __restrict__ seg,
    const unsigned short* __restrict__ weights, float* __restrict__ sums,
    float* __restrict__ deg, int n_edges) {
  const int lane = threadIdx.x & 63;
  const int wib = threadIdx.x >> 6;
  const int e16 = lane >> 2;   // edge within group
  const int j = lane & 3;      // output quad (quad-coalesced loads)

  const long wbase = (long)blockIdx.x * 128 + wib * 32;
  long eA = wbase + e16;
  long eB = eA + 16;
  const bool vA = eA < n_edges;
  const bool vB = eB < n_edges;
  if (!vA) eA = n_edges - 1;
  if (!vB) eB = n_edges - 1;

  const int sA = seg[eA];
  const int nA = idxn[eA];
  const int fA = idxe[eA];
  const int sB = seg[eB];
  const int nB = idxn[eB];
  const int fB = idxe[eB];

  // Issue ALL 18 vector loads.
  fvec4 xoA = ((const fvec4*)(input + (size_t)nA * IN_CH))[j];
  const uvec4* __restrict__ wqA = (const uvec4*)(weights + (size_t)fA * WROW);
  uvec4 wvA[8];
  #pragma unroll
  for (int u = 0; u < 8; ++u) wvA[u] = wqA[u * 4 + j];
  fvec4 xoB = ((const fvec4*)(input + (size_t)nB * IN_CH))[j];
  const uvec4* __restrict__ wqB = (const uvec4*)(weights + (size_t)fB * WROW);
  uvec4 wvB[8];
  #pragma unroll
  for (int u = 0; u < 8; ++u) wvB[u] = wqB[u * 4 + j];

  // Pin A (read-write: consumers below depend on the asm's outputs, so they
  // cannot hoist above it; compiler emits a partial vmcnt leaving B in
  // flight). Then compute A while B's loads complete; pin B; compute B.
  asm volatile("" : "+v"(wvA[0]), "+v"(wvA[1]), "+v"(wvA[2]), "+v"(wvA[3]),
                    "+v"(wvA[4]), "+v"(wvA[5]), "+v"(wvA[6]), "+v"(wvA[7]),
                    "+v"(xoA));
  const fvec4 accA = edge_dot(xoA, wvA);
  asm volatile("" : "+v"(wvB[0]), "+v"(wvB[1]), "+v"(wvB[2]), "+v"(wvB[3]),
                    "+v"(wvB[4]), "+v"(wvB[5]), "+v"(wvB[6]), "+v"(wvB[7]),
                    "+v"(xoB));
  const fvec4 accB = edge_dot(xoB, wvB);

  seg_reduce_flush(sA, accA, 1.f, vA, lane, e16, j, sums, deg);
  seg_reduce_flush(sB, accB, 1.f, vB, lane, e16, j, sums, deg);
}

// ---------------- Kernel 3: divide by degree --------------------------------
__global__ __launch_bounds__(256) void finalize_kernel(
    const float* __restrict__ sums, const float* __restrict__ deg,
    float* __restrict__ out, int n_nodes) {
  const int n = blockIdx.x * blockDim.x + threadIdx.x;
  if (n >= n_nodes) return;
  const float d = deg[n];
  const float scale = d > 0.f ? 1.f / d : 0.f;
  const float4* sp = (const float4*)(sums + (size_t)n * OUT_CH);
  float4* op = (float4*)(out + (size_t)n * OUT_CH);
  #pragma unroll
  for (int q = 0; q < 4; ++q) {
    float4 v = sp[q];
    v.x *= scale; v.y *= scale; v.z *= scale; v.w *= scale;
    op[q] = v;
  }
}

extern "C" void kernel_launch(void* const* d_in, const int* in_sizes, int n_in,
                              void* d_out, int out_size, void* d_ws, size_t ws_size,
                              hipStream_t stream) {
  const float* input = (const float*)d_in[0];
  const int* idxn    = (const int*)d_in[1];
  const int* idxe    = (const int*)d_in[2];
  const int* seg     = (const int*)d_in[3];
  const float* ef    = (const float*)d_in[4];
  const float* W1    = (const float*)d_in[5];
  const float* b1    = (const float*)d_in[6];
  const float* W2    = (const float*)d_in[7];
  const float* b2    = (const float*)d_in[8];
  float* out = (float*)d_out;

  const int n_nodes   = in_sizes[0] / IN_CH;
  const int n_edges   = in_sizes[1];
  const int n_filters = in_sizes[4] / EDGE_FEAT;

  // workspace: f16 weights [F*256] (2 MB) | sums [n_nodes*16] | deg [n_nodes]
  unsigned short* weights = (unsigned short*)d_ws;
  float* sums = (float*)((char*)d_ws + (size_t)n_filters * WROW * sizeof(unsigned short));
  float* deg  = sums + (size_t)n_nodes * OUT_CH;

  // filter_net also zeroes sums|deg (contiguous region, float4-aligned).
  const int nzero4 = (n_nodes * (OUT_CH + 1)) / 4;
  filter_net_kernel<<<n_filters / FN_FPB, 256, 0, stream>>>(
      ef, W1, b1, W2, b2, weights, sums, nzero4);

  // 128 edges per 256-thread block (2 groups of 16 per wave).
  const long n_blocks = ((long)n_edges + 127) / 128;
  edge_kernel<<<(int)n_blocks, 256, 0, stream>>>(
      input, idxn, idxe, seg, weights, sums, deg, n_edges);

  finalize_kernel<<<(n_nodes + 255) / 256, 256, 0, stream>>>(sums, deg, out,
                                                             n_nodes);
}

// Round 12
// 148.759 us; speedup vs baseline: 1.1286x; 1.1286x over previous
//
#include <hip/hip_runtime.h>

#define IN_CH 16
#define OUT_CH 16
#define EDGE_FEAT 32
#define HIDDEN 128
#define WROW 256          // IN_CH*OUT_CH
#define FN_FPB 8          // filters per block in filter-net kernel
#define SLOTS 256         // max runs per 256-edge block (<=64 per wave)
#define LSTR 17           // LDS floats per slot: 16 channels + count

typedef __fp16 half2_v __attribute__((ext_vector_type(2)));
typedef unsigned uvec4 __attribute__((ext_vector_type(4)));
typedef float fvec4 __attribute__((ext_vector_type(4)));

__device__ __forceinline__ unsigned pk_f16(float lo, float hi) {
  half2_v h = __builtin_amdgcn_cvt_pkrtz(lo, hi);
  return __builtin_bit_cast(unsigned, h);
}

__device__ __forceinline__ float dot2(unsigned wpair, half2_v xp, float acc) {
  half2_v w = __builtin_bit_cast(half2_v, wpair);
#if __has_builtin(__builtin_amdgcn_fdot2)
  return __builtin_amdgcn_fdot2(xp, w, acc, false);
#else
  acc = fmaf((float)xp[0], (float)w[0], acc);
  return fmaf((float)xp[1], (float)w[1], acc);
#endif
}

// ---------------- Kernel 1: filter net (f16 pair-layout output) -------------
__global__ __launch_bounds__(256) void filter_net_kernel(
    const float* __restrict__ ef, const float* __restrict__ W1,
    const float* __restrict__ b1, const float* __restrict__ W2,
    const float* __restrict__ b2, unsigned short* __restrict__ weights,
    float* __restrict__ zero_base, int nzero4) {
  const int t = threadIdx.x;
  const int f0 = blockIdx.x * FN_FPB;

  for (int gid = blockIdx.x * 256 + t; gid < nzero4; gid += gridDim.x * 256)
    ((float4*)zero_base)[gid] = make_float4(0.f, 0.f, 0.f, 0.f);

  __shared__ float ef_s[FN_FPB * EDGE_FEAT];
  __shared__ float h_s[FN_FPB][HIDDEN];
  ef_s[t] = ef[f0 * EDGE_FEAT + t];
  __syncthreads();

  #pragma unroll
  for (int r = 0; r < 4; ++r) {
    const int idx = t + r * 256;
    const int fi = idx >> 7;
    const int hi = idx & (HIDDEN - 1);
    float a = b1[hi];
    #pragma unroll
    for (int k = 0; k < EDGE_FEAT; ++k)
      a = fmaf(ef_s[fi * EDGE_FEAT + k], W1[k * HIDDEN + hi], a);
    h_s[fi][hi] = a > 0.f ? a : 0.f;
  }
  __syncthreads();

  const int fslot = t >> 5;
  const int combo = t & 31;
  const int u = combo >> 2;
  const int jo = combo & 3;
  const int colLo = 32 * u + 4 * jo;
  const int colHi = colLo + 16;

  float4 aLo = *(const float4*)(b2 + colLo);
  float4 aHi = *(const float4*)(b2 + colHi);
  const float* __restrict__ hrow = h_s[fslot];
  #pragma unroll 4
  for (int k = 0; k < HIDDEN; ++k) {
    const float4 wLo = *(const float4*)(W2 + (size_t)k * WROW + colLo);
    const float4 wHi = *(const float4*)(W2 + (size_t)k * WROW + colHi);
    const float hv = hrow[k];
    aLo.x = fmaf(hv, wLo.x, aLo.x);
    aLo.y = fmaf(hv, wLo.y, aLo.y);
    aLo.z = fmaf(hv, wLo.z, aLo.z);
    aLo.w = fmaf(hv, wLo.w, aLo.w);
    aHi.x = fmaf(hv, wHi.x, aHi.x);
    aHi.y = fmaf(hv, wHi.y, aHi.y);
    aHi.z = fmaf(hv, wHi.z, aHi.z);
    aHi.w = fmaf(hv, wHi.w, aHi.w);
  }

  uint4 st;
  st.x = pk_f16(aLo.x, aHi.x);
  st.y = pk_f16(aLo.y, aHi.y);
  st.z = pk_f16(aLo.z, aHi.z);
  st.w = pk_f16(aLo.w, aHi.w);
  *(uint4*)(weights + (size_t)(f0 + fslot) * WROW + (u * 4 + jo) * 8) = st;
}

// ---------------- Kernel 2: 64 edges/wave, LDS run accumulation -------------
// Memory-instruction budget per 64-edge wave (the binding resource at
// ~14.3 cy/instr): 3 idx + 32 weight + 4 x + ~2 global-atomic = ~41
// (was 68). Aggregation: run rank via ballot+popcount, per-phase DPP row
// reduction, ds_add into per-block LDS slots, one coalesced atomic flush.

template <int CTRL, int OLD>
__device__ __forceinline__ int dpp_i(int v) {
  return __builtin_amdgcn_update_dpp(OLD, v, CTRL, 0xf, 0xf, false);
}
template <int CTRL>
__device__ __forceinline__ float dpp_f(float v) {
  return __builtin_bit_cast(
      float, __builtin_amdgcn_update_dpp(0, __builtin_bit_cast(int, v), CTRL,
                                         0xf, 0xf, false));
}
template <int Q>
__device__ __forceinline__ int quad_bcast_dpp(int v) {
  return __builtin_amdgcn_update_dpp(0, v, Q * 0x55, 0xf, 0xf, false);
}

// suffix-combine within a 16-lane row (4 edges), keyed on slot equality.
template <int CTRL>
__device__ __forceinline__ void seg_step_dpp(int sl, fvec4& acc, float& cnt) {
  const int os = dpp_i<CTRL, -1>(sl);
  const float ox = dpp_f<CTRL>(acc.x);
  const float oy = dpp_f<CTRL>(acc.y);
  const float oz = dpp_f<CTRL>(acc.z);
  const float ow = dpp_f<CTRL>(acc.w);
  const float oc = dpp_f<CTRL>(cnt);
  if (os == sl) {
    acc.x += ox; acc.y += oy; acc.z += oz; acc.w += ow;
    cnt += oc;
  }
}

__device__ __forceinline__ fvec4 edge_dot(const fvec4 xo, const uvec4* wv) {
  const int p0 = (int)pk_f16(xo.x, xo.y);
  const int p1 = (int)pk_f16(xo.z, xo.w);
  half2_v xp[8];
  xp[0] = __builtin_bit_cast(half2_v, quad_bcast_dpp<0>(p0));
  xp[1] = __builtin_bit_cast(half2_v, quad_bcast_dpp<0>(p1));
  xp[2] = __builtin_bit_cast(half2_v, quad_bcast_dpp<1>(p0));
  xp[3] = __builtin_bit_cast(half2_v, quad_bcast_dpp<1>(p1));
  xp[4] = __builtin_bit_cast(half2_v, quad_bcast_dpp<2>(p0));
  xp[5] = __builtin_bit_cast(half2_v, quad_bcast_dpp<2>(p1));
  xp[6] = __builtin_bit_cast(half2_v, quad_bcast_dpp<3>(p0));
  xp[7] = __builtin_bit_cast(half2_v, quad_bcast_dpp<3>(p1));

  fvec4 acc = {0.f, 0.f, 0.f, 0.f};
  #pragma unroll
  for (int u = 0; u < 8; ++u) {
    acc.x = dot2(wv[u].x, xp[u], acc.x);
    acc.y = dot2(wv[u].y, xp[u], acc.y);
    acc.z = dot2(wv[u].z, xp[u], acc.z);
    acc.w = dot2(wv[u].w, xp[u], acc.w);
  }
  return acc;
}

__global__ __launch_bounds__(256) void edge_kernel(
    const float* __restrict__ input, const int* __restrict__ idxn,
    const int* __restrict__ idxe, const int* __restrict__ seg,
    const unsigned short* __restrict__ weights, float* __restrict__ sums,
    float* __restrict__ deg, int n_edges) {
  __shared__ float lds_acc[SLOTS * LSTR];   // 17.4 KB
  __shared__ int lds_map[SLOTS];
  __shared__ int lds_wcnt[4];

  const int t = threadIdx.x;
  const int lane = t & 63;
  const int w = t >> 6;
  const int e16 = lane >> 2;
  const int j = lane & 3;

  const long wv_base = (long)blockIdx.x * 256 + w * 64;

  // coalesced per-lane edge metadata (3 mem instrs for 64 edges)
  long el = wv_base + lane;
  const bool vl = el < n_edges;
  if (!vl) el = n_edges - 1;
  const int s_l = seg[el];
  const int n_l = idxn[el];
  const int f_l = idxe[el];
  const int sv = vl ? s_l : -1;

  // run heads within this wave; rank via ballot+popcount (VALU only)
  const int sprev = __shfl(sv, (lane - 1) & 63);
  const bool head = vl && (lane == 0 || sprev != sv);
  const unsigned long long bal = __ballot(head);
  const int r = (int)__popcll(bal & ((1ull << lane) - 1ull));

  // zero LDS accumulators (1088 float4)
  {
    float4* a4 = (float4*)lds_acc;
    #pragma unroll
    for (int k = 0; k < 4; ++k)
      a4[t + k * 256] = make_float4(0.f, 0.f, 0.f, 0.f);
    if (t < SLOTS * LSTR / 4 - 1024)
      a4[1024 + t] = make_float4(0.f, 0.f, 0.f, 0.f);
  }
  if (lane == 0) lds_wcnt[w] = (int)__popcll(bal);
  __syncthreads();

  int rb = 0;
  if (w > 0) rb += lds_wcnt[0];
  if (w > 1) rb += lds_wcnt[1];
  if (w > 2) rb += lds_wcnt[2];
  const int R = lds_wcnt[0] + lds_wcnt[1] + lds_wcnt[2] + lds_wcnt[3];

  const int slot_l = rb + r - (head ? 0 : 1);
  if (head) lds_map[slot_l] = sv;

  // 4 phases of 16 edges; quad layout (lane = e16*4 + j) keeps every
  // weight-load quad on one 64 B line.
  #pragma unroll
  for (int g = 0; g < 4; ++g) {
    const int src = g * 16 + e16;
    const int fg = __shfl(f_l, src);
    const int ng = __shfl(n_l, src);
    const int sl = __shfl(slot_l, src);
    const bool ve = (wv_base + src) < n_edges;

    const fvec4 xo = ((const fvec4*)(input + (size_t)ng * IN_CH))[j];
    const uvec4* __restrict__ wq = (const uvec4*)(weights + (size_t)fg * WROW);
    uvec4 wv[8];
    #pragma unroll
    for (int u = 0; u < 8; ++u) wv[u] = wq[u * 4 + j];

    fvec4 acc = edge_dot(xo, wv);
    float cnt = ve ? 1.f : 0.f;
    if (!ve) { acc.x = 0.f; acc.y = 0.f; acc.z = 0.f; acc.w = 0.f; }

    // row-local suffix combine (4 edges per 16-lane row), keyed on slot
    seg_step_dpp<0x104>(sl, acc, cnt);   // + next edge
    seg_step_dpp<0x108>(sl, acc, cnt);   // + edges +2,+3
    const int pslot = dpp_i<0x114, -1>(sl);  // prev edge's slot (row_shr:4)
    if (ve && pslot != sl) {             // sub-run head -> LDS accumulate
      float* p = lds_acc + sl * LSTR + j * 4;
      atomicAdd(p + 0, acc.x);
      atomicAdd(p + 1, acc.y);
      atomicAdd(p + 2, acc.z);
      atomicAdd(p + 3, acc.w);
      if (j == 0) atomicAdd(lds_acc + sl * LSTR + 16, cnt);
    }
  }
  __syncthreads();

  // flush: one (slot, channel) pair per thread; R is typically ~12 -> one
  // iteration = 2 global atomic instrs per wave.
  const int ch = t & 15;
  for (int slot = t >> 4; slot < R; slot += 16) {
    const int node = lds_map[slot];
    atomicAdd(sums + (size_t)node * OUT_CH + ch, lds_acc[slot * LSTR + ch]);
    if (ch == 0) atomicAdd(deg + node, lds_acc[slot * LSTR + 16]);
  }
}

// ---------------- Kernel 3: divide by degree --------------------------------
__global__ __launch_bounds__(256) void finalize_kernel(
    const float* __restrict__ sums, const float* __restrict__ deg,
    float* __restrict__ out, int n_nodes) {
  const int n = blockIdx.x * blockDim.x + threadIdx.x;
  if (n >= n_nodes) return;
  const float d = deg[n];
  const float scale = d > 0.f ? 1.f / d : 0.f;
  const float4* sp = (const float4*)(sums + (size_t)n * OUT_CH);
  float4* op = (float4*)(out + (size_t)n * OUT_CH);
  #pragma unroll
  for (int q = 0; q < 4; ++q) {
    float4 v = sp[q];
    v.x *= scale; v.y *= scale; v.z *= scale; v.w *= scale;
    op[q] = v;
  }
}

extern "C" void kernel_launch(void* const* d_in, const int* in_sizes, int n_in,
                              void* d_out, int out_size, void* d_ws, size_t ws_size,
                              hipStream_t stream) {
  const float* input = (const float*)d_in[0];
  const int* idxn    = (const int*)d_in[1];
  const int* idxe    = (const int*)d_in[2];
  const int* seg     = (const int*)d_in[3];
  const float* ef    = (const float*)d_in[4];
  const float* W1    = (const float*)d_in[5];
  const float* b1    = (const float*)d_in[6];
  const float* W2    = (const float*)d_in[7];
  const float* b2    = (const float*)d_in[8];
  float* out = (float*)d_out;

  const int n_nodes   = in_sizes[0] / IN_CH;
  const int n_edges   = in_sizes[1];
  const int n_filters = in_sizes[4] / EDGE_FEAT;

  // workspace: f16 weights [F*256] (2 MB) | sums [n_nodes*16] | deg [n_nodes]
  unsigned short* weights = (unsigned short*)d_ws;
  float* sums = (float*)((char*)d_ws + (size_t)n_filters * WROW * sizeof(unsigned short));
  float* deg  = sums + (size_t)n_nodes * OUT_CH;

  const int nzero4 = (n_nodes * (OUT_CH + 1)) / 4;
  filter_net_kernel<<<n_filters / FN_FPB, 256, 0, stream>>>(
      ef, W1, b1, W2, b2, weights, sums, nzero4);

  // 256 edges per block (64 per wave).
  const long n_blocks = ((long)n_edges + 255) / 256;
  edge_kernel<<<(int)n_blocks, 256, 0, stream>>>(
      input, idxn, idxe, seg, weights, sums, deg, n_edges);

  finalize_kernel<<<(n_nodes + 255) / 256, 256, 0, stream>>>(sums, deg, out,
                                                             n_nodes);
}

// Round 13
// 148.398 us; speedup vs baseline: 1.1313x; 1.0024x over previous
//
#include <hip/hip_runtime.h>

#define IN_CH 16
#define OUT_CH 16
#define EDGE_FEAT 32
#define HIDDEN 128
#define WROW 256          // IN_CH*OUT_CH
#define FN_FPB 8          // filters per block in filter-net kernel
#define WSLOTS 64         // per-wave run slots (worst case: 64 runs of len 1)
#define LSTR 17           // LDS floats per slot: 16 channels + count

typedef __fp16 half2_v __attribute__((ext_vector_type(2)));
typedef unsigned uvec4 __attribute__((ext_vector_type(4)));
typedef float fvec4 __attribute__((ext_vector_type(4)));

__device__ __forceinline__ unsigned pk_f16(float lo, float hi) {
  half2_v h = __builtin_amdgcn_cvt_pkrtz(lo, hi);
  return __builtin_bit_cast(unsigned, h);
}

__device__ __forceinline__ float dot2(unsigned wpair, half2_v xp, float acc) {
  half2_v w = __builtin_bit_cast(half2_v, wpair);
#if __has_builtin(__builtin_amdgcn_fdot2)
  return __builtin_amdgcn_fdot2(xp, w, acc, false);
#else
  acc = fmaf((float)xp[0], (float)w[0], acc);
  return fmaf((float)xp[1], (float)w[1], acc);
#endif
}

// ---------------- Kernel 1: filter net (f16 pair-layout output) -------------
__global__ __launch_bounds__(256) void filter_net_kernel(
    const float* __restrict__ ef, const float* __restrict__ W1,
    const float* __restrict__ b1, const float* __restrict__ W2,
    const float* __restrict__ b2, unsigned short* __restrict__ weights,
    float* __restrict__ zero_base, int nzero4) {
  const int t = threadIdx.x;
  const int f0 = blockIdx.x * FN_FPB;

  for (int gid = blockIdx.x * 256 + t; gid < nzero4; gid += gridDim.x * 256)
    ((float4*)zero_base)[gid] = make_float4(0.f, 0.f, 0.f, 0.f);

  __shared__ float ef_s[FN_FPB * EDGE_FEAT];
  __shared__ float h_s[FN_FPB][HIDDEN];
  ef_s[t] = ef[f0 * EDGE_FEAT + t];
  __syncthreads();

  #pragma unroll
  for (int r = 0; r < 4; ++r) {
    const int idx = t + r * 256;
    const int fi = idx >> 7;
    const int hi = idx & (HIDDEN - 1);
    float a = b1[hi];
    #pragma unroll
    for (int k = 0; k < EDGE_FEAT; ++k)
      a = fmaf(ef_s[fi * EDGE_FEAT + k], W1[k * HIDDEN + hi], a);
    h_s[fi][hi] = a > 0.f ? a : 0.f;
  }
  __syncthreads();

  const int fslot = t >> 5;
  const int combo = t & 31;
  const int u = combo >> 2;
  const int jo = combo & 3;
  const int colLo = 32 * u + 4 * jo;
  const int colHi = colLo + 16;

  float4 aLo = *(const float4*)(b2 + colLo);
  float4 aHi = *(const float4*)(b2 + colHi);
  const float* __restrict__ hrow = h_s[fslot];
  #pragma unroll 4
  for (int k = 0; k < HIDDEN; ++k) {
    const float4 wLo = *(const float4*)(W2 + (size_t)k * WROW + colLo);
    const float4 wHi = *(const float4*)(W2 + (size_t)k * WROW + colHi);
    const float hv = hrow[k];
    aLo.x = fmaf(hv, wLo.x, aLo.x);
    aLo.y = fmaf(hv, wLo.y, aLo.y);
    aLo.z = fmaf(hv, wLo.z, aLo.z);
    aLo.w = fmaf(hv, wLo.w, aLo.w);
    aHi.x = fmaf(hv, wHi.x, aHi.x);
    aHi.y = fmaf(hv, wHi.y, aHi.y);
    aHi.z = fmaf(hv, wHi.z, aHi.z);
    aHi.w = fmaf(hv, wHi.w, aHi.w);
  }

  uint4 st;
  st.x = pk_f16(aLo.x, aHi.x);
  st.y = pk_f16(aLo.y, aHi.y);
  st.z = pk_f16(aLo.z, aHi.z);
  st.w = pk_f16(aLo.w, aHi.w);
  *(uint4*)(weights + (size_t)(f0 + fslot) * WROW + (u * 4 + jo) * 8) = st;
}

// ---------------- Kernel 2: 64 edges/wave, wave-private LDS slots -----------
// r12 minus its overhead: slot assignment/accumulation/flush are wave-local,
// so each wave owns a private 64-slot LDS range -> NO __syncthreads, no
// cross-wave count exchange, zeroing only the ~r_w live slots, 1-iter flush.
// Weight loads: byte base + immediate offsets (1 addr calc per 8 loads).

template <int CTRL, int OLD>
__device__ __forceinline__ int dpp_i(int v) {
  return __builtin_amdgcn_update_dpp(OLD, v, CTRL, 0xf, 0xf, false);
}
template <int CTRL>
__device__ __forceinline__ float dpp_f(float v) {
  return __builtin_bit_cast(
      float, __builtin_amdgcn_update_dpp(0, __builtin_bit_cast(int, v), CTRL,
                                         0xf, 0xf, false));
}
template <int Q>
__device__ __forceinline__ int quad_bcast_dpp(int v) {
  return __builtin_amdgcn_update_dpp(0, v, Q * 0x55, 0xf, 0xf, false);
}

template <int CTRL>
__device__ __forceinline__ void seg_step_dpp(int sl, fvec4& acc, float& cnt) {
  const int os = dpp_i<CTRL, -1>(sl);
  const float ox = dpp_f<CTRL>(acc.x);
  const float oy = dpp_f<CTRL>(acc.y);
  const float oz = dpp_f<CTRL>(acc.z);
  const float ow = dpp_f<CTRL>(acc.w);
  const float oc = dpp_f<CTRL>(cnt);
  if (os == sl) {
    acc.x += ox; acc.y += oy; acc.z += oz; acc.w += ow;
    cnt += oc;
  }
}

__device__ __forceinline__ fvec4 edge_dot(const fvec4 xo, const uvec4* wv) {
  const int p0 = (int)pk_f16(xo.x, xo.y);
  const int p1 = (int)pk_f16(xo.z, xo.w);
  half2_v xp[8];
  xp[0] = __builtin_bit_cast(half2_v, quad_bcast_dpp<0>(p0));
  xp[1] = __builtin_bit_cast(half2_v, quad_bcast_dpp<0>(p1));
  xp[2] = __builtin_bit_cast(half2_v, quad_bcast_dpp<1>(p0));
  xp[3] = __builtin_bit_cast(half2_v, quad_bcast_dpp<1>(p1));
  xp[4] = __builtin_bit_cast(half2_v, quad_bcast_dpp<2>(p0));
  xp[5] = __builtin_bit_cast(half2_v, quad_bcast_dpp<2>(p1));
  xp[6] = __builtin_bit_cast(half2_v, quad_bcast_dpp<3>(p0));
  xp[7] = __builtin_bit_cast(half2_v, quad_bcast_dpp<3>(p1));

  fvec4 acc = {0.f, 0.f, 0.f, 0.f};
  #pragma unroll
  for (int u = 0; u < 8; ++u) {
    acc.x = dot2(wv[u].x, xp[u], acc.x);
    acc.y = dot2(wv[u].y, xp[u], acc.y);
    acc.z = dot2(wv[u].z, xp[u], acc.z);
    acc.w = dot2(wv[u].w, xp[u], acc.w);
  }
  return acc;
}

__global__ __launch_bounds__(256) void edge_kernel(
    const float* __restrict__ input, const int* __restrict__ idxn,
    const int* __restrict__ idxe, const int* __restrict__ seg,
    const unsigned short* __restrict__ weights, float* __restrict__ sums,
    float* __restrict__ deg, int n_edges) {
  __shared__ float lds_acc[4][WSLOTS * LSTR];   // 4 x 4352 B (wave-private)
  __shared__ int lds_map[4][WSLOTS];

  const int t = threadIdx.x;
  const int lane = t & 63;
  const int w = t >> 6;
  const int e16 = lane >> 2;
  const int j = lane & 3;
  float* __restrict__ acc_w = lds_acc[w];

  const long wv_base = (long)blockIdx.x * 256 + w * 64;

  // coalesced per-lane edge metadata (3 mem instrs for 64 edges)
  long el = wv_base + lane;
  const bool vl = el < n_edges;
  if (!vl) el = n_edges - 1;
  const int s_l = seg[el];
  const int n_l = idxn[el];
  const int f_l = idxe[el];
  const int sv = vl ? s_l : -1;

  // run heads within this wave; rank via ballot+popcount (VALU only)
  const int sprev = __shfl(sv, (lane - 1) & 63);
  const bool head = vl && (lane == 0 || sprev != sv);
  const unsigned long long bal = __ballot(head);
  const int r = (int)__popcll(bal & ((1ull << lane) - 1ull));
  const int r_w = (int)__popcll(bal);           // runs in this wave

  // zero only the live slots of this wave's range (typically 1 iteration)
  for (int idx = lane; idx < r_w * LSTR; idx += 64) acc_w[idx] = 0.f;

  const int slot_l = r - (head ? 0 : 1);
  if (head) lds_map[w][slot_l] = sv;

  // 4 phases of 16 edges; quad layout (lane = e16*4 + j) keeps every
  // weight-load quad on one 64 B line.
  #pragma unroll
  for (int g = 0; g < 4; ++g) {
    const int src = g * 16 + e16;
    const int fg = __shfl(f_l, src);
    const int ng = __shfl(n_l, src);
    const int sl = __shfl(slot_l, src);
    const bool ve = (wv_base + src) < n_edges;

    // one address per lane; 8 loads use immediate offsets u*64
    const char* __restrict__ wb =
        (const char*)weights + (((size_t)fg << 9) | (j << 4));
    uvec4 wv[8];
    #pragma unroll
    for (int u = 0; u < 8; ++u) wv[u] = *(const uvec4*)(wb + (u << 6));
    const fvec4 xo = *(const fvec4*)(input + ((size_t)ng << 4) + (j << 2));

    fvec4 acc = edge_dot(xo, wv);
    float cnt = ve ? 1.f : 0.f;
    if (!ve) { acc.x = 0.f; acc.y = 0.f; acc.z = 0.f; acc.w = 0.f; }

    // row-local suffix combine (4 edges per 16-lane row), keyed on slot
    seg_step_dpp<0x104>(sl, acc, cnt);       // + next edge
    seg_step_dpp<0x108>(sl, acc, cnt);       // + edges +2,+3
    const int pslot = dpp_i<0x114, -1>(sl);  // prev edge's slot (row_shr:4)
    if (ve && pslot != sl) {                 // sub-run head -> LDS accumulate
      float* p = acc_w + sl * LSTR + j * 4;
      atomicAdd(p + 0, acc.x);
      atomicAdd(p + 1, acc.y);
      atomicAdd(p + 2, acc.z);
      atomicAdd(p + 3, acc.w);
      if (j == 0) atomicAdd(acc_w + sl * LSTR + 16, cnt);
    }
  }

  // drain this wave's DS queue before reading its slots (no barrier needed:
  // everything is wave-local).
  asm volatile("s_waitcnt lgkmcnt(0)" ::: "memory");

  // flush this wave's runs: 4 slots per iteration (typically 1 iteration).
  const int ch = lane & 15;
  for (int slot = lane >> 4; slot < r_w; slot += 4) {
    const int node = lds_map[w][slot];
    atomicAdd(sums + ((size_t)node << 4) + ch, acc_w[slot * LSTR + ch]);
    if (ch == 0) atomicAdd(deg + node, acc_w[slot * LSTR + 16]);
  }
}

// ---------------- Kernel 3: divide by degree --------------------------------
__global__ __launch_bounds__(256) void finalize_kernel(
    const float* __restrict__ sums, const float* __restrict__ deg,
    float* __restrict__ out, int n_nodes) {
  const int n = blockIdx.x * blockDim.x + threadIdx.x;
  if (n >= n_nodes) return;
  const float d = deg[n];
  const float scale = d > 0.f ? 1.f / d : 0.f;
  const float4* sp = (const float4*)(sums + (size_t)n * OUT_CH);
  float4* op = (float4*)(out + (size_t)n * OUT_CH);
  #pragma unroll
  for (int q = 0; q < 4; ++q) {
    float4 v = sp[q];
    v.x *= scale; v.y *= scale; v.z *= scale; v.w *= scale;
    op[q] = v;
  }
}

extern "C" void kernel_launch(void* const* d_in, const int* in_sizes, int n_in,
                              void* d_out, int out_size, void* d_ws, size_t ws_size,
                              hipStream_t stream) {
  const float* input = (const float*)d_in[0];
  const int* idxn    = (const int*)d_in[1];
  const int* idxe    = (const int*)d_in[2];
  const int* seg     = (const int*)d_in[3];
  const float* ef    = (const float*)d_in[4];
  const float* W1    = (const float*)d_in[5];
  const float* b1    = (const float*)d_in[6];
  const float* W2    = (const float*)d_in[7];
  const float* b2    = (const float*)d_in[8];
  float* out = (float*)d_out;

  const int n_nodes   = in_sizes[0] / IN_CH;
  const int n_edges   = in_sizes[1];
  const int n_filters = in_sizes[4] / EDGE_FEAT;

  // workspace: f16 weights [F*256] (2 MB) | sums [n_nodes*16] | deg [n_nodes]
  unsigned short* weights = (unsigned short*)d_ws;
  float* sums = (float*)((char*)d_ws + (size_t)n_filters * WROW * sizeof(unsigned short));
  float* deg  = sums + (size_t)n_nodes * OUT_CH;

  const int nzero4 = (n_nodes * (OUT_CH + 1)) / 4;
  filter_net_kernel<<<n_filters / FN_FPB, 256, 0, stream>>>(
      ef, W1, b1, W2, b2, weights, sums, nzero4);

  // 256 edges per block (64 per wave).
  const long n_blocks = ((long)n_edges + 255) / 256;
  edge_kernel<<<(int)n_blocks, 256, 0, stream>>>(
      input, idxn, idxe, seg, weights, sums, deg, n_edges);

  finalize_kernel<<<(n_nodes + 255) / 256, 256, 0, stream>>>(sums, deg, out,
                                                             n_nodes);
}

// Round 14
// 143.410 us; speedup vs baseline: 1.1707x; 1.0348x over previous
//
#include <hip/hip_runtime.h>

#define IN_CH 16
#define OUT_CH 16
#define EDGE_FEAT 32
#define HIDDEN 128
#define WROW 256          // IN_CH*OUT_CH
#define FN_FPB 16         // filters per block in filter-net kernel
#define WSLOTS 64         // per-wave run slots
#define LSTR 16           // LDS floats per slot (16 channels; cnt derived)

typedef __fp16 half2_v __attribute__((ext_vector_type(2)));
typedef unsigned uvec4 __attribute__((ext_vector_type(4)));
typedef float fvec4 __attribute__((ext_vector_type(4)));

__device__ __forceinline__ unsigned pk_f16(float lo, float hi) {
  half2_v h = __builtin_amdgcn_cvt_pkrtz(lo, hi);
  return __builtin_bit_cast(unsigned, h);
}

__device__ __forceinline__ float dot2(unsigned wpair, half2_v xp, float acc) {
  half2_v w = __builtin_bit_cast(half2_v, wpair);
#if __has_builtin(__builtin_amdgcn_fdot2)
  return __builtin_amdgcn_fdot2(xp, w, acc, false);
#else
  acc = fmaf((float)xp[0], (float)w[0], acc);
  return fmaf((float)xp[1], (float)w[1], acc);
#endif
}

// ---------------- Kernel 1: filter net v2 -----------------------------------
// 16 filters/block, 256 blocks. Stage-2: thread owns one float4 column for
// FOUR filters -> 1 W2 float4 load amortized over 16 FMA (4x fewer VMEM
// instrs than r13). f16 pair (i=2u, 2u+1) formed via shfl_xor(4) partner.
__global__ __launch_bounds__(256) void filter_net_kernel(
    const float* __restrict__ ef, const float* __restrict__ W1,
    const float* __restrict__ b1, const float* __restrict__ W2,
    const float* __restrict__ b2, unsigned short* __restrict__ weights,
    float* __restrict__ zero_base, int nzero4) {
  const int t = threadIdx.x;
  const int f0 = blockIdx.x * FN_FPB;

  for (int gid = blockIdx.x * 256 + t; gid < nzero4; gid += gridDim.x * 256)
    ((float4*)zero_base)[gid] = make_float4(0.f, 0.f, 0.f, 0.f);

  __shared__ float ef_s[FN_FPB * EDGE_FEAT];   // 2 KB
  __shared__ float h_s[FN_FPB][HIDDEN];        // 8 KB
  ef_s[t] = ef[f0 * EDGE_FEAT + t];
  ef_s[t + 256] = ef[f0 * EDGE_FEAT + t + 256];
  __syncthreads();

  // stage 1: 2048 h values, 8 per thread (hi = t&127, filters fb..fb+7).
  {
    const int hi = t & 127;
    const int fb = (t >> 7) * 8;
    float a[8];
    #pragma unroll
    for (int r = 0; r < 8; ++r) a[r] = b1[hi];
    for (int k0 = 0; k0 < EDGE_FEAT; k0 += 4) {
      float w1v[4];
      #pragma unroll
      for (int m = 0; m < 4; ++m) w1v[m] = W1[(k0 + m) * HIDDEN + hi];
      #pragma unroll
      for (int r = 0; r < 8; ++r) {
        const float4 e4 = *(const float4*)&ef_s[(fb + r) * EDGE_FEAT + k0];
        a[r] = fmaf(e4.x, w1v[0], a[r]);
        a[r] = fmaf(e4.y, w1v[1], a[r]);
        a[r] = fmaf(e4.z, w1v[2], a[r]);
        a[r] = fmaf(e4.w, w1v[3], a[r]);
      }
    }
    #pragma unroll
    for (int r = 0; r < 8; ++r) h_s[fb + r][hi] = a[r] > 0.f ? a[r] : 0.f;
  }
  __syncthreads();

  // stage 2: cq = t&63 owns cols 4cq..4cq+3 for filters grp*4..grp*4+3.
  const int cq = t & 63;
  const int grp = t >> 6;
  float4 facc[4];
  const float4 bb = *(const float4*)(b2 + 4 * cq);
  #pragma unroll
  for (int q = 0; q < 4; ++q) facc[q] = bb;
  for (int k0 = 0; k0 < HIDDEN; k0 += 4) {
    float4 w2v[4];
    #pragma unroll
    for (int m = 0; m < 4; ++m)
      w2v[m] = ((const float4*)(W2 + (size_t)(k0 + m) * WROW))[cq];
    #pragma unroll
    for (int q = 0; q < 4; ++q) {
      const float4 h4 = *(const float4*)&h_s[grp * 4 + q][k0];
      facc[q].x = fmaf(h4.x, w2v[0].x, facc[q].x);
      facc[q].y = fmaf(h4.x, w2v[0].y, facc[q].y);
      facc[q].z = fmaf(h4.x, w2v[0].z, facc[q].z);
      facc[q].w = fmaf(h4.x, w2v[0].w, facc[q].w);
      facc[q].x = fmaf(h4.y, w2v[1].x, facc[q].x);
      facc[q].y = fmaf(h4.y, w2v[1].y, facc[q].y);
      facc[q].z = fmaf(h4.y, w2v[1].z, facc[q].z);
      facc[q].w = fmaf(h4.y, w2v[1].w, facc[q].w);
      facc[q].x = fmaf(h4.z, w2v[2].x, facc[q].x);
      facc[q].y = fmaf(h4.z, w2v[2].y, facc[q].y);
      facc[q].z = fmaf(h4.z, w2v[2].z, facc[q].z);
      facc[q].w = fmaf(h4.z, w2v[2].w, facc[q].w);
      facc[q].x = fmaf(h4.w, w2v[3].x, facc[q].x);
      facc[q].y = fmaf(h4.w, w2v[3].y, facc[q].y);
      facc[q].z = fmaf(h4.w, w2v[3].z, facc[q].z);
      facc[q].w = fmaf(h4.w, w2v[3].w, facc[q].w);
    }
  }

  // epilogue: cols 4cq+m -> (i = cq>>2, o = 4*(cq&3)+m). Partner thread
  // cq^4 holds i^1 (same jo). Even-i thread packs (w[2u][o], w[2u+1][o]).
  const int i = cq >> 2;
  const int jo = cq & 3;
  const int u = i >> 1;
  #pragma unroll
  for (int q = 0; q < 4; ++q) {
    float4 oth;
    oth.x = __shfl_xor(facc[q].x, 4);
    oth.y = __shfl_xor(facc[q].y, 4);
    oth.z = __shfl_xor(facc[q].z, 4);
    oth.w = __shfl_xor(facc[q].w, 4);
    if ((i & 1) == 0) {
      uint4 st;
      st.x = pk_f16(facc[q].x, oth.x);
      st.y = pk_f16(facc[q].y, oth.y);
      st.z = pk_f16(facc[q].z, oth.z);
      st.w = pk_f16(facc[q].w, oth.w);
      *(uint4*)(weights + (size_t)(f0 + grp * 4 + q) * WROW +
                (u * 4 + jo) * 8) = st;
    }
  }
}

// ---------------- Kernel 2: pipelined phases + wave-private LDS slots -------
template <int CTRL, int OLD>
__device__ __forceinline__ int dpp_i(int v) {
  return __builtin_amdgcn_update_dpp(OLD, v, CTRL, 0xf, 0xf, false);
}
template <int CTRL>
__device__ __forceinline__ float dpp_f(float v) {
  return __builtin_bit_cast(
      float, __builtin_amdgcn_update_dpp(0, __builtin_bit_cast(int, v), CTRL,
                                         0xf, 0xf, false));
}
template <int Q>
__device__ __forceinline__ int quad_bcast_dpp(int v) {
  return __builtin_amdgcn_update_dpp(0, v, Q * 0x55, 0xf, 0xf, false);
}

template <int CTRL>
__device__ __forceinline__ void seg_step_dpp(int sl, fvec4& acc) {
  const int os = dpp_i<CTRL, -1>(sl);
  const float ox = dpp_f<CTRL>(acc.x);
  const float oy = dpp_f<CTRL>(acc.y);
  const float oz = dpp_f<CTRL>(acc.z);
  const float ow = dpp_f<CTRL>(acc.w);
  if (os == sl) {
    acc.x += ox; acc.y += oy; acc.z += oz; acc.w += ow;
  }
}

__device__ __forceinline__ fvec4 edge_dot(const fvec4 xo, const uvec4* wv) {
  const int p0 = (int)pk_f16(xo.x, xo.y);
  const int p1 = (int)pk_f16(xo.z, xo.w);
  half2_v xp[8];
  xp[0] = __builtin_bit_cast(half2_v, quad_bcast_dpp<0>(p0));
  xp[1] = __builtin_bit_cast(half2_v, quad_bcast_dpp<0>(p1));
  xp[2] = __builtin_bit_cast(half2_v, quad_bcast_dpp<1>(p0));
  xp[3] = __builtin_bit_cast(half2_v, quad_bcast_dpp<1>(p1));
  xp[4] = __builtin_bit_cast(half2_v, quad_bcast_dpp<2>(p0));
  xp[5] = __builtin_bit_cast(half2_v, quad_bcast_dpp<2>(p1));
  xp[6] = __builtin_bit_cast(half2_v, quad_bcast_dpp<3>(p0));
  xp[7] = __builtin_bit_cast(half2_v, quad_bcast_dpp<3>(p1));

  fvec4 acc = {0.f, 0.f, 0.f, 0.f};
  #pragma unroll
  for (int u = 0; u < 8; ++u) {
    acc.x = dot2(wv[u].x, xp[u], acc.x);
    acc.y = dot2(wv[u].y, xp[u], acc.y);
    acc.z = dot2(wv[u].z, xp[u], acc.z);
    acc.w = dot2(wv[u].w, xp[u], acc.w);
  }
  return acc;
}

__global__ __launch_bounds__(256) void edge_kernel(
    const float* __restrict__ input, const int* __restrict__ idxn,
    const int* __restrict__ idxe, const int* __restrict__ seg,
    const unsigned short* __restrict__ weights, float* __restrict__ sums,
    float* __restrict__ deg, int n_edges) {
  __shared__ float lds_acc[4][WSLOTS * LSTR];   // 4 x 4 KB (wave-private)
  __shared__ int lds_map[4][WSLOTS];

  const int t = threadIdx.x;
  const int lane = t & 63;
  const int w = t >> 6;
  const int e16 = lane >> 2;
  const int j = lane & 3;
  float* __restrict__ acc_w = lds_acc[w];

  const long wv_base = (long)blockIdx.x * 256 + w * 64;
  long rem = n_edges - wv_base;
  const int valid_cnt = rem < 0 ? 0 : (rem > 64 ? 64 : (int)rem);

  long el = wv_base + lane;
  const bool vl = el < n_edges;
  if (!vl) el = n_edges - 1;
  const int s_l = seg[el];
  const int n_l = idxn[el];
  const int f_l = idxe[el];
  const int sv = vl ? s_l : -1;

  const int sprev = __shfl(sv, (lane - 1) & 63);
  const bool head = vl && (lane == 0 || sprev != sv);
  const unsigned long long bal = __ballot(head);
  const int r = (int)__popcll(bal & ((1ull << lane) - 1ull));
  const int r_w = (int)__popcll(bal);

  for (int idx = lane; idx < r_w * LSTR; idx += 64) acc_w[idx] = 0.f;

  const int slot_l = r - (head ? 0 : 1);
  if (head) lds_map[w][slot_l] = (lane << 20) | sv;   // head lane + node id

  // all-phase metadata up front
  int fgv[4], ngv[4], slv[4];
  #pragma unroll
  for (int g = 0; g < 4; ++g) {
    const int src = g * 16 + e16;
    fgv[g] = __shfl(f_l, src);
    ngv[g] = __shfl(n_l, src);
    slv[g] = __shfl(slot_l, src);
  }

  uvec4 wvA[8], wvB[8];
  fvec4 xoA, xoB;

  auto loadp = [&](int g, uvec4* wv, fvec4& xo) {
    const char* __restrict__ wb =
        (const char*)weights + (((size_t)fgv[g] << 9) | (j << 4));
    #pragma unroll
    for (int u = 0; u < 8; ++u) wv[u] = *(const uvec4*)(wb + (u << 6));
    xo = *(const fvec4*)(input + ((size_t)ngv[g] << 4) + (j << 2));
  };

  auto compute = [&](int g, const uvec4* wv, const fvec4& xo) {
    const int sl = slv[g];
    const bool ve = (g * 16 + e16) < valid_cnt;
    fvec4 acc = edge_dot(xo, wv);
    if (!ve) { acc.x = 0.f; acc.y = 0.f; acc.z = 0.f; acc.w = 0.f; }
    seg_step_dpp<0x104>(sl, acc);            // + next edge (within row)
    seg_step_dpp<0x108>(sl, acc);            // + edges +2,+3
    const int pslot = dpp_i<0x114, -1>(sl);  // prev edge's slot
    if (ve && pslot != sl) {
      float* p = acc_w + sl * LSTR + j * 4;
      atomicAdd(p + 0, acc.x);
      atomicAdd(p + 1, acc.y);
      atomicAdd(p + 2, acc.z);
      atomicAdd(p + 3, acc.w);
    }
  };

  // 2-deep software pipeline; sched_barrier keeps each prefetch batch
  // issued above the previous phase's compute.
  loadp(0, wvA, xoA);
  loadp(1, wvB, xoB);
  __builtin_amdgcn_sched_barrier(0);
  compute(0, wvA, xoA);
  loadp(2, wvA, xoA);
  __builtin_amdgcn_sched_barrier(0);
  compute(1, wvB, xoB);
  loadp(3, wvB, xoB);
  __builtin_amdgcn_sched_barrier(0);
  compute(2, wvA, xoA);
  compute(3, wvB, xoB);

  // drain wave-local DS before reading slots (no barrier: wave-private).
  asm volatile("s_waitcnt lgkmcnt(0)" ::: "memory");

  const int ch = lane & 15;
  for (int slot = lane >> 4; slot < r_w; slot += 4) {
    const int m0 = lds_map[w][slot];
    const int node = m0 & 0xFFFFF;
    atomicAdd(sums + ((size_t)node << 4) + ch, acc_w[slot * LSTR + ch]);
    if (ch == 0) {
      const int start = m0 >> 20;
      const int end =
          (slot + 1 < r_w) ? (lds_map[w][slot + 1] >> 20) : valid_cnt;
      atomicAdd(deg + node, (float)(end - start));
    }
  }
}

// ---------------- Kernel 3: divide by degree --------------------------------
__global__ __launch_bounds__(256) void finalize_kernel(
    const float* __restrict__ sums, const float* __restrict__ deg,
    float* __restrict__ out, int n_nodes) {
  const int n = blockIdx.x * blockDim.x + threadIdx.x;
  if (n >= n_nodes) return;
  const float d = deg[n];
  const float scale = d > 0.f ? 1.f / d : 0.f;
  const float4* sp = (const float4*)(sums + (size_t)n * OUT_CH);
  float4* op = (float4*)(out + (size_t)n * OUT_CH);
  #pragma unroll
  for (int q = 0; q < 4; ++q) {
    float4 v = sp[q];
    v.x *= scale; v.y *= scale; v.z *= scale; v.w *= scale;
    op[q] = v;
  }
}

extern "C" void kernel_launch(void* const* d_in, const int* in_sizes, int n_in,
                              void* d_out, int out_size, void* d_ws, size_t ws_size,
                              hipStream_t stream) {
  const float* input = (const float*)d_in[0];
  const int* idxn    = (const int*)d_in[1];
  const int* idxe    = (const int*)d_in[2];
  const int* seg     = (const int*)d_in[3];
  const float* ef    = (const float*)d_in[4];
  const float* W1    = (const float*)d_in[5];
  const float* b1    = (const float*)d_in[6];
  const float* W2    = (const float*)d_in[7];
  const float* b2    = (const float*)d_in[8];
  float* out = (float*)d_out;

  const int n_nodes   = in_sizes[0] / IN_CH;
  const int n_edges   = in_sizes[1];
  const int n_filters = in_sizes[4] / EDGE_FEAT;

  // workspace: f16 weights [F*256] (2 MB) | sums [n_nodes*16] | deg [n_nodes]
  unsigned short* weights = (unsigned short*)d_ws;
  float* sums = (float*)((char*)d_ws + (size_t)n_filters * WROW * sizeof(unsigned short));
  float* deg  = sums + (size_t)n_nodes * OUT_CH;

  const int nzero4 = (n_nodes * (OUT_CH + 1)) / 4;
  filter_net_kernel<<<n_filters / FN_FPB, 256, 0, stream>>>(
      ef, W1, b1, W2, b2, weights, sums, nzero4);

  const long n_blocks = ((long)n_edges + 255) / 256;
  edge_kernel<<<(int)n_blocks, 256, 0, stream>>>(
      input, idxn, idxe, seg, weights, sums, deg, n_edges);

  finalize_kernel<<<(n_nodes + 255) / 256, 256, 0, stream>>>(sums, deg, out,
                                                             n_nodes);
}

// Round 15
// 141.173 us; speedup vs baseline: 1.1892x; 1.0158x over previous
//
#include <hip/hip_runtime.h>

#define IN_CH 16
#define OUT_CH 16
#define EDGE_FEAT 32
#define HIDDEN 128
#define WROW 256          // IN_CH*OUT_CH
#define FN_FPB 16         // filters per block in filter-net kernel
#define WSLOTS 64         // per-wave run slots
#define LSTR 16           // LDS floats per slot (16 channels; deg derived)

typedef __fp16 half2_v __attribute__((ext_vector_type(2)));
typedef unsigned uvec4 __attribute__((ext_vector_type(4)));
typedef float fvec4 __attribute__((ext_vector_type(4)));

__device__ __forceinline__ unsigned pk_f16(float lo, float hi) {
  half2_v h = __builtin_amdgcn_cvt_pkrtz(lo, hi);
  return __builtin_bit_cast(unsigned, h);
}

__device__ __forceinline__ float dot2(unsigned wpair, half2_v xp, float acc) {
  half2_v w = __builtin_bit_cast(half2_v, wpair);
#if __has_builtin(__builtin_amdgcn_fdot2)
  return __builtin_amdgcn_fdot2(xp, w, acc, false);
#else
  acc = fmaf((float)xp[0], (float)w[0], acc);
  return fmaf((float)xp[1], (float)w[1], acc);
#endif
}

// ---------------- Kernel 1: filter net v2 (r14, measured -7 µs) -------------
__global__ __launch_bounds__(256) void filter_net_kernel(
    const float* __restrict__ ef, const float* __restrict__ W1,
    const float* __restrict__ b1, const float* __restrict__ W2,
    const float* __restrict__ b2, unsigned short* __restrict__ weights,
    float* __restrict__ zero_base, int nzero4) {
  const int t = threadIdx.x;
  const int f0 = blockIdx.x * FN_FPB;

  for (int gid = blockIdx.x * 256 + t; gid < nzero4; gid += gridDim.x * 256)
    ((float4*)zero_base)[gid] = make_float4(0.f, 0.f, 0.f, 0.f);

  __shared__ float ef_s[FN_FPB * EDGE_FEAT];   // 2 KB
  __shared__ float h_s[FN_FPB][HIDDEN];        // 8 KB
  ef_s[t] = ef[f0 * EDGE_FEAT + t];
  ef_s[t + 256] = ef[f0 * EDGE_FEAT + t + 256];
  __syncthreads();

  // stage 1: 2048 h values, 8 per thread.
  {
    const int hi = t & 127;
    const int fb = (t >> 7) * 8;
    float a[8];
    #pragma unroll
    for (int r = 0; r < 8; ++r) a[r] = b1[hi];
    for (int k0 = 0; k0 < EDGE_FEAT; k0 += 4) {
      float w1v[4];
      #pragma unroll
      for (int m = 0; m < 4; ++m) w1v[m] = W1[(k0 + m) * HIDDEN + hi];
      #pragma unroll
      for (int r = 0; r < 8; ++r) {
        const float4 e4 = *(const float4*)&ef_s[(fb + r) * EDGE_FEAT + k0];
        a[r] = fmaf(e4.x, w1v[0], a[r]);
        a[r] = fmaf(e4.y, w1v[1], a[r]);
        a[r] = fmaf(e4.z, w1v[2], a[r]);
        a[r] = fmaf(e4.w, w1v[3], a[r]);
      }
    }
    #pragma unroll
    for (int r = 0; r < 8; ++r) h_s[fb + r][hi] = a[r] > 0.f ? a[r] : 0.f;
  }
  __syncthreads();

  // stage 2: cq owns cols 4cq..4cq+3 for filters grp*4..grp*4+3.
  const int cq = t & 63;
  const int grp = t >> 6;
  float4 facc[4];
  const float4 bb = *(const float4*)(b2 + 4 * cq);
  #pragma unroll
  for (int q = 0; q < 4; ++q) facc[q] = bb;
  for (int k0 = 0; k0 < HIDDEN; k0 += 4) {
    float4 w2v[4];
    #pragma unroll
    for (int m = 0; m < 4; ++m)
      w2v[m] = ((const float4*)(W2 + (size_t)(k0 + m) * WROW))[cq];
    #pragma unroll
    for (int q = 0; q < 4; ++q) {
      const float4 h4 = *(const float4*)&h_s[grp * 4 + q][k0];
      facc[q].x = fmaf(h4.x, w2v[0].x, facc[q].x);
      facc[q].y = fmaf(h4.x, w2v[0].y, facc[q].y);
      facc[q].z = fmaf(h4.x, w2v[0].z, facc[q].z);
      facc[q].w = fmaf(h4.x, w2v[0].w, facc[q].w);
      facc[q].x = fmaf(h4.y, w2v[1].x, facc[q].x);
      facc[q].y = fmaf(h4.y, w2v[1].y, facc[q].y);
      facc[q].z = fmaf(h4.y, w2v[1].z, facc[q].z);
      facc[q].w = fmaf(h4.y, w2v[1].w, facc[q].w);
      facc[q].x = fmaf(h4.z, w2v[2].x, facc[q].x);
      facc[q].y = fmaf(h4.z, w2v[2].y, facc[q].y);
      facc[q].z = fmaf(h4.z, w2v[2].z, facc[q].z);
      facc[q].w = fmaf(h4.z, w2v[2].w, facc[q].w);
      facc[q].x = fmaf(h4.w, w2v[3].x, facc[q].x);
      facc[q].y = fmaf(h4.w, w2v[3].y, facc[q].y);
      facc[q].z = fmaf(h4.w, w2v[3].z, facc[q].z);
      facc[q].w = fmaf(h4.w, w2v[3].w, facc[q].w);
    }
  }

  const int i = cq >> 2;
  const int jo = cq & 3;
  const int u = i >> 1;
  #pragma unroll
  for (int q = 0; q < 4; ++q) {
    float4 oth;
    oth.x = __shfl_xor(facc[q].x, 4);
    oth.y = __shfl_xor(facc[q].y, 4);
    oth.z = __shfl_xor(facc[q].z, 4);
    oth.w = __shfl_xor(facc[q].w, 4);
    if ((i & 1) == 0) {
      uint4 st;
      st.x = pk_f16(facc[q].x, oth.x);
      st.y = pk_f16(facc[q].y, oth.y);
      st.z = pk_f16(facc[q].z, oth.z);
      st.w = pk_f16(facc[q].w, oth.w);
      *(uint4*)(weights + (size_t)(f0 + grp * 4 + q) * WROW +
                (u * 4 + jo) * 8) = st;
    }
  }
}

// ---------------- Kernel 2: r13 scheduling + cnt-free scan ------------------
template <int CTRL, int OLD>
__device__ __forceinline__ int dpp_i(int v) {
  return __builtin_amdgcn_update_dpp(OLD, v, CTRL, 0xf, 0xf, false);
}
template <int CTRL>
__device__ __forceinline__ float dpp_f(float v) {
  return __builtin_bit_cast(
      float, __builtin_amdgcn_update_dpp(0, __builtin_bit_cast(int, v), CTRL,
                                         0xf, 0xf, false));
}
template <int Q>
__device__ __forceinline__ int quad_bcast_dpp(int v) {
  return __builtin_amdgcn_update_dpp(0, v, Q * 0x55, 0xf, 0xf, false);
}

template <int CTRL>
__device__ __forceinline__ void seg_step_dpp(int sl, fvec4& acc) {
  const int os = dpp_i<CTRL, -1>(sl);
  const float ox = dpp_f<CTRL>(acc.x);
  const float oy = dpp_f<CTRL>(acc.y);
  const float oz = dpp_f<CTRL>(acc.z);
  const float ow = dpp_f<CTRL>(acc.w);
  if (os == sl) {
    acc.x += ox; acc.y += oy; acc.z += oz; acc.w += ow;
  }
}

__device__ __forceinline__ fvec4 edge_dot(const fvec4 xo, const uvec4* wv) {
  const int p0 = (int)pk_f16(xo.x, xo.y);
  const int p1 = (int)pk_f16(xo.z, xo.w);
  half2_v xp[8];
  xp[0] = __builtin_bit_cast(half2_v, quad_bcast_dpp<0>(p0));
  xp[1] = __builtin_bit_cast(half2_v, quad_bcast_dpp<0>(p1));
  xp[2] = __builtin_bit_cast(half2_v, quad_bcast_dpp<1>(p0));
  xp[3] = __builtin_bit_cast(half2_v, quad_bcast_dpp<1>(p1));
  xp[4] = __builtin_bit_cast(half2_v, quad_bcast_dpp<2>(p0));
  xp[5] = __builtin_bit_cast(half2_v, quad_bcast_dpp<2>(p1));
  xp[6] = __builtin_bit_cast(half2_v, quad_bcast_dpp<3>(p0));
  xp[7] = __builtin_bit_cast(half2_v, quad_bcast_dpp<3>(p1));

  fvec4 acc = {0.f, 0.f, 0.f, 0.f};
  #pragma unroll
  for (int u = 0; u < 8; ++u) {
    acc.x = dot2(wv[u].x, xp[u], acc.x);
    acc.y = dot2(wv[u].y, xp[u], acc.y);
    acc.z = dot2(wv[u].z, xp[u], acc.z);
    acc.w = dot2(wv[u].w, xp[u], acc.w);
  }
  return acc;
}

__global__ __launch_bounds__(256) void edge_kernel(
    const float* __restrict__ input, const int* __restrict__ idxn,
    const int* __restrict__ idxe, const int* __restrict__ seg,
    const unsigned short* __restrict__ weights, float* __restrict__ sums,
    float* __restrict__ deg, int n_edges) {
  __shared__ float lds_acc[4][WSLOTS * LSTR];   // 4 x 4 KB (wave-private)
  __shared__ int lds_map[4][WSLOTS];

  const int t = threadIdx.x;
  const int lane = t & 63;
  const int w = t >> 6;
  const int e16 = lane >> 2;
  const int j = lane & 3;
  float* __restrict__ acc_w = lds_acc[w];

  const long wv_base = (long)blockIdx.x * 256 + w * 64;
  long rem = n_edges - wv_base;
  const int valid_cnt = rem < 0 ? 0 : (rem > 64 ? 64 : (int)rem);

  long el = wv_base + lane;
  const bool vl = el < n_edges;
  if (!vl) el = n_edges - 1;
  const int s_l = seg[el];
  const int n_l = idxn[el];
  const int f_l = idxe[el];
  const int sv = vl ? s_l : -1;

  const int sprev = __shfl(sv, (lane - 1) & 63);
  const bool head = vl && (lane == 0 || sprev != sv);
  const unsigned long long bal = __ballot(head);
  const int r = (int)__popcll(bal & ((1ull << lane) - 1ull));
  const int r_w = (int)__popcll(bal);

  for (int idx = lane; idx < r_w * LSTR; idx += 64) acc_w[idx] = 0.f;

  const int slot_l = r - (head ? 0 : 1);
  if (head) lds_map[w][slot_l] = (lane << 20) | sv;   // head lane | node id

  // 4 phases of 16 edges; r13 relaxed scheduling (shuffles in-loop, no
  // sched_barrier — the compiler's interleave beat the pinned pipeline).
  #pragma unroll
  for (int g = 0; g < 4; ++g) {
    const int src = g * 16 + e16;
    const int fg = __shfl(f_l, src);
    const int ng = __shfl(n_l, src);
    const int sl = __shfl(slot_l, src);
    const bool ve = src < valid_cnt;

    const char* __restrict__ wb =
        (const char*)weights + (((size_t)fg << 9) | (j << 4));
    uvec4 wv[8];
    #pragma unroll
    for (int u = 0; u < 8; ++u) wv[u] = *(const uvec4*)(wb + (u << 6));
    const fvec4 xo = *(const fvec4*)(input + ((size_t)ng << 4) + (j << 2));

    fvec4 acc = edge_dot(xo, wv);
    if (!ve) { acc.x = 0.f; acc.y = 0.f; acc.z = 0.f; acc.w = 0.f; }

    seg_step_dpp<0x104>(sl, acc);            // + next edge (within row)
    seg_step_dpp<0x108>(sl, acc);            // + edges +2,+3
    const int pslot = dpp_i<0x114, -1>(sl);  // prev edge's slot
    if (ve && pslot != sl) {                 // sub-run head -> LDS accumulate
      float* p = acc_w + sl * LSTR + j * 4;
      atomicAdd(p + 0, acc.x);
      atomicAdd(p + 1, acc.y);
      atomicAdd(p + 2, acc.z);
      atomicAdd(p + 3, acc.w);
    }
  }

  // drain wave-local DS before reading slots (no barrier: wave-private).
  asm volatile("s_waitcnt lgkmcnt(0)" ::: "memory");

  // flush; deg derived from head-lane deltas (no cnt accumulation).
  const int ch = lane & 15;
  for (int slot = lane >> 4; slot < r_w; slot += 4) {
    const int m0 = lds_map[w][slot];
    const int node = m0 & 0xFFFFF;
    atomicAdd(sums + ((size_t)node << 4) + ch, acc_w[slot * LSTR + ch]);
    if (ch == 0) {
      const int start = m0 >> 20;
      const int end =
          (slot + 1 < r_w) ? (lds_map[w][slot + 1] >> 20) : valid_cnt;
      atomicAdd(deg + node, (float)(end - start));
    }
  }
}

// ---------------- Kernel 3: divide by degree --------------------------------
__global__ __launch_bounds__(256) void finalize_kernel(
    const float* __restrict__ sums, const float* __restrict__ deg,
    float* __restrict__ out, int n_nodes) {
  const int n = blockIdx.x * blockDim.x + threadIdx.x;
  if (n >= n_nodes) return;
  const float d = deg[n];
  const float scale = d > 0.f ? 1.f / d : 0.f;
  const float4* sp = (const float4*)(sums + (size_t)n * OUT_CH);
  float4* op = (float4*)(out + (size_t)n * OUT_CH);
  #pragma unroll
  for (int q = 0; q < 4; ++q) {
    float4 v = sp[q];
    v.x *= scale; v.y *= scale; v.z *= scale; v.w *= scale;
    op[q] = v;
  }
}

extern "C" void kernel_launch(void* const* d_in, const int* in_sizes, int n_in,
                              void* d_out, int out_size, void* d_ws, size_t ws_size,
                              hipStream_t stream) {
  const float* input = (const float*)d_in[0];
  const int* idxn    = (const int*)d_in[1];
  const int* idxe    = (const int*)d_in[2];
  const int* seg     = (const int*)d_in[3];
  const float* ef    = (const float*)d_in[4];
  const float* W1    = (const float*)d_in[5];
  const float* b1    = (const float*)d_in[6];
  const float* W2    = (const float*)d_in[7];
  const float* b2    = (const float*)d_in[8];
  float* out = (float*)d_out;

  const int n_nodes   = in_sizes[0] / IN_CH;
  const int n_edges   = in_sizes[1];
  const int n_filters = in_sizes[4] / EDGE_FEAT;

  // workspace: f16 weights [F*256] (2 MB) | sums [n_nodes*16] | deg [n_nodes]
  unsigned short* weights = (unsigned short*)d_ws;
  float* sums = (float*)((char*)d_ws + (size_t)n_filters * WROW * sizeof(unsigned short));
  float* deg  = sums + (size_t)n_nodes * OUT_CH;

  const int nzero4 = (n_nodes * (OUT_CH + 1)) / 4;
  filter_net_kernel<<<n_filters / FN_FPB, 256, 0, stream>>>(
      ef, W1, b1, W2, b2, weights, sums, nzero4);

  const long n_blocks = ((long)n_edges + 255) / 256;
  edge_kernel<<<(int)n_blocks, 256, 0, stream>>>(
      input, idxn, idxe, seg, weights, sums, deg, n_edges);

  finalize_kernel<<<(n_nodes + 255) / 256, 256, 0, stream>>>(sums, deg, out,
                                                             n_nodes);
}